// Round 10
// baseline (185.393 us; speedup 1.0000x reference)
//
#include <hip/hip_runtime.h>
#include <math.h>

// flash-decode, GQA paged KV. R=4, B=16, Hq=32, Hk=8 (G=4), D=128, P=8192,
// PAGE=1, M=2048.
// Storage (confirmed round 7): q/k_cache/v_cache are FLOAT32 on device;
// lens/block_table int32; out float32.
//
// Round 10: remove the 4x redundant K/V loads (round 8/9 gave each GQA head
// g its own wave walking ALL tokens). Now each wave owns a QUARTER of the
// token range and computes all 4 g-dots per token (4 q vectors in regs).
// 1-deep double-buffered K/V prefetch with named A/B buffers (static
// indexing only). Softmax in log2-domain (exp2f = raw v_exp_f32).
// Split-KV S=16; LSE-weighted combine kernel unchanged (exp2f domain).

typedef float f32x4 __attribute__((ext_vector_type(4)));

#define R_ 4
#define B_ 16
#define HQ_ 32
#define HK_ 8
#define G_ 4
#define D_ 128
#define P_ 8192
#define M_ 2048
#define HKD (HK_ * D_)
// (1/sqrt(128)) * log2(e): scores tracked in log2-domain
#define SC2 (0.08838834764831845f * 1.4426950408889634f)

__device__ __forceinline__ void load8f(const float* p, float o[8]) {
  f32x4 a = *(const f32x4*)p;
  f32x4 b = *(const f32x4*)(p + 4);
#pragma unroll
  for (int j = 0; j < 4; ++j) { o[j] = a[j]; o[4 + j] = b[j]; }
}

__device__ __forceinline__ int clampP(int p) {
  return p < 0 ? 0 : (p >= P_ ? P_ - 1 : p);
}

// ---------------- kernel 1: per-(r,b,hk,split) partials ----------------
__global__ __launch_bounds__(256, 4) void fd_partial(
    const float* __restrict__ q, const float* __restrict__ kc,
    const float* __restrict__ vc, const int* __restrict__ lens,
    const int* __restrict__ bt, float* __restrict__ ws_m,
    float* __restrict__ ws_l, float* __restrict__ ws_o, int S) {
  const int idx = blockIdx.x;
  const int s = idx % S;
  const int hk = (idx / S) % HK_;
  const int b = (idx / (S * HK_)) % B_;
  const int r = idx / (S * HK_ * B_);

  const int lane = threadIdx.x & 63;
  const int w = threadIdx.x >> 6;  // wave id == token-quarter
  const int tg = lane >> 4;        // slot 0..3: one token per slot per step
  const int ds = (lane & 15) * 8;  // dim slice [ds, ds+8)

  float q0[8], q1[8], q2[8], q3[8];
  {
    const float* qp = q + (size_t)(b * HQ_ + hk * G_) * D_ + ds;
    load8f(qp, q0);
    load8f(qp + D_, q1);
    load8f(qp + 2 * D_, q2);
    load8f(qp + 3 * D_, q3);
  }

  int kvlen = lens[r * B_ + b];
  if (kvlen < 0) kvlen = 0;
  if (kvlen > M_) kvlen = M_;
  const int chunk = (((kvlen + S - 1) / S) + 15) & ~15;  // 16-aligned
  const int t0 = s * chunk;
  int t1 = t0 + chunk;
  if (t1 > kvlen) t1 = kvlen;
  const int qc = chunk >> 2;  // per-wave tokens (multiple of 4)
  const int w0 = t0 + w * qc;
  int w1 = w0 + qc;
  if (w1 > t1) w1 = t1;

  const int* btrow = bt + (r * B_ + b) * M_;
  const float* kb = kc + (size_t)r * P_ * HKD + (size_t)hk * D_ + ds;
  const float* vb = vc + (size_t)r * P_ * HKD + (size_t)hk * D_ + ds;

  float m0 = -INFINITY, m1 = -INFINITY, m2 = -INFINITY, m3 = -INFINITY;
  float l0 = 0.f, l1 = 0.f, l2 = 0.f, l3 = 0.f;
  float a0[8], a1[8], a2[8], a3[8];
#pragma unroll
  for (int j = 0; j < 8; ++j) { a0[j] = 0.f; a1[j] = 0.f; a2[j] = 0.f; a3[j] = 0.f; }

  auto upd = [&](float& m, float& l, float(&a)[8], float d, bool vld,
                 const float(&vv)[8]) {
    float sS = vld ? d * SC2 : -INFINITY;
    float mn = fmaxf(m, sS);
    if (mn > -INFINITY) {
      float sc = (m > -INFINITY) ? exp2f(m - mn) : 0.f;
      float p = (sS > -INFINITY) ? exp2f(sS - mn) : 0.f;
      m = mn;
      l = l * sc + p;
#pragma unroll
      for (int j = 0; j < 8; ++j) a[j] = a[j] * sc + p * vv[j];
    }
  };

  auto step = [&](int t, float(&kcur)[8], float(&vcur)[8], float(&knxt)[8],
                  float(&vnxt)[8]) {
    // prefetch token t+4+tg into the alternate buffers (masked to safe addr)
    const int tn = t + 4 + tg;
    const bool vldn = tn < w1;
    const int pgn = clampP(btrow[vldn ? tn : w0]);
    load8f(kb + (size_t)pgn * HKD, knxt);
    load8f(vb + (size_t)pgn * HKD, vnxt);

    const bool vld = (t + tg) < w1;
    float d0 = 0.f, d1 = 0.f, d2 = 0.f, d3 = 0.f;
#pragma unroll
    for (int j = 0; j < 8; ++j) {
      d0 += q0[j] * kcur[j];
      d1 += q1[j] * kcur[j];
      d2 += q2[j] * kcur[j];
      d3 += q3[j] * kcur[j];
    }
#pragma unroll
    for (int msk = 1; msk <= 8; msk <<= 1) {
      d0 += __shfl_xor(d0, msk);
      d1 += __shfl_xor(d1, msk);
      d2 += __shfl_xor(d2, msk);
      d3 += __shfl_xor(d3, msk);
    }
    upd(m0, l0, a0, d0, vld, vcur);
    upd(m1, l1, a1, d1, vld, vcur);
    upd(m2, l2, a2, d2, vld, vcur);
    upd(m3, l3, a3, d3, vld, vcur);
  };

  if (w0 < w1) {
    float kA[8], vA[8], kB[8], vB[8];
    {
      const int tok = w0 + tg;
      const bool v = tok < w1;
      const int pg = clampP(btrow[v ? tok : w0]);
      load8f(kb + (size_t)pg * HKD, kA);
      load8f(vb + (size_t)pg * HKD, vA);
    }
    for (int t = w0; t < w1; t += 8) {
      step(t, kA, vA, kB, vB);
      if (t + 4 < w1) step(t + 4, kB, vB, kA, vA);
    }
  }

  // intra-wave merge of the 4 token slots (xor 16, 32) per head
  auto slotmerge = [&](float& m, float& l, float(&a)[8]) {
#pragma unroll
    for (int off = 16; off <= 32; off <<= 1) {
      const float mo = __shfl_xor(m, off);
      const float lo = __shfl_xor(l, off);
      float ao[8];
#pragma unroll
      for (int j = 0; j < 8; ++j) ao[j] = __shfl_xor(a[j], off);
      const float mn = fmaxf(m, mo);
      const float se = (m > -INFINITY) ? exp2f(m - mn) : 0.f;
      const float so_ = (mo > -INFINITY) ? exp2f(mo - mn) : 0.f;
      l = l * se + lo * so_;
#pragma unroll
      for (int j = 0; j < 8; ++j) a[j] = a[j] * se + ao[j] * so_;
      m = mn;
    }
  };
  slotmerge(m0, l0, a0);
  slotmerge(m1, l1, a1);
  slotmerge(m2, l2, a2);
  slotmerge(m3, l3, a3);

  // cross-wave merge via LDS; wave w then finalizes head g = w
  __shared__ float sm[4][G_], sl[4][G_], so[4][G_][D_];
  if (lane < 16) {
#pragma unroll
    for (int j = 0; j < 8; ++j) {
      so[w][0][ds + j] = a0[j];
      so[w][1][ds + j] = a1[j];
      so[w][2][ds + j] = a2[j];
      so[w][3][ds + j] = a3[j];
    }
    if (lane == 0) {
      sm[w][0] = m0; sm[w][1] = m1; sm[w][2] = m2; sm[w][3] = m3;
      sl[w][0] = l0; sl[w][1] = l1; sl[w][2] = l2; sl[w][3] = l3;
    }
  }
  __syncthreads();

  const int rec = blockIdx.x;  // == ((r*B+b)*HK + hk)*S + s
  const int g = w;
  const float mw0 = sm[0][g], mw1 = sm[1][g], mw2 = sm[2][g], mw3 = sm[3][g];
  const float mf = fmaxf(fmaxf(mw0, mw1), fmaxf(mw2, mw3));
  const float wt0 = (mw0 > -INFINITY) ? exp2f(mw0 - mf) : 0.f;
  const float wt1 = (mw1 > -INFINITY) ? exp2f(mw1 - mf) : 0.f;
  const float wt2 = (mw2 > -INFINITY) ? exp2f(mw2 - mf) : 0.f;
  const float wt3 = (mw3 > -INFINITY) ? exp2f(mw3 - mf) : 0.f;
  const float lf = wt0 * sl[0][g] + wt1 * sl[1][g] + wt2 * sl[2][g] +
                   wt3 * sl[3][g];
  const float of0 = wt0 * so[0][g][lane] + wt1 * so[1][g][lane] +
                    wt2 * so[2][g][lane] + wt3 * so[3][g][lane];
  const float of1 = wt0 * so[0][g][lane + 64] + wt1 * so[1][g][lane + 64] +
                    wt2 * so[2][g][lane + 64] + wt3 * so[3][g][lane + 64];
  ws_o[((size_t)rec * G_ + g) * D_ + lane] = of0;
  ws_o[((size_t)rec * G_ + g) * D_ + lane + 64] = of1;
  if (lane == 0) {
    ws_m[rec * G_ + g] = mf;  // log2-domain
    ws_l[rec * G_ + g] = lf;
  }
}

// ---------------- kernel 2: LSE-weighted combine over R*S ----------------
__global__ __launch_bounds__(128) void fd_reduce(
    const float* __restrict__ ws_m, const float* __restrict__ ws_l,
    const float* __restrict__ ws_o, float* __restrict__ out, int S) {
  const int row = blockIdx.x;  // (b*HK + hk)*G + g
  const int g = row % G_;
  const int hk = (row / G_) % HK_;
  const int b = row / (G_ * HK_);
  const int d = threadIdx.x;

  float mf = -INFINITY;
  for (int r = 0; r < R_; ++r)
    for (int s = 0; s < S; ++s) {
      int rec = ((r * B_ + b) * HK_ + hk) * S + s;
      mf = fmaxf(mf, ws_m[rec * G_ + g]);
    }
  float of = 0.f, lf = 0.f;
  for (int r = 0; r < R_; ++r)
    for (int s = 0; s < S; ++s) {
      int rec = ((r * B_ + b) * HK_ + hk) * S + s;
      float wm = ws_m[rec * G_ + g];
      if (wm == -INFINITY) continue;
      float wt = exp2f(wm - mf);  // log2-domain partials
      of += wt * ws_o[((size_t)rec * G_ + g) * D_ + d];
      lf += wt * ws_l[rec * G_ + g];
    }
  out[(size_t)(b * HQ_ + hk * G_ + g) * D_ + d] = of / lf;
}

// ---------------- fallback: monolithic (tiny workspace) ----------------
__global__ __launch_bounds__(256) void fd_mono(
    const float* __restrict__ q, const float* __restrict__ kc,
    const float* __restrict__ vc, const int* __restrict__ lens,
    const int* __restrict__ bt, float* __restrict__ out) {
  const int hk = blockIdx.x % HK_;
  const int b = blockIdx.x / HK_;
  const int lane = threadIdx.x & 63;
  const int g = threadIdx.x >> 6;
  const int tg = lane >> 4;
  const int ds = (lane & 15) * 8;

  float qf[8];
  load8f(q + (size_t)(b * HQ_ + hk * G_ + g) * D_ + ds, qf);

  float m = -INFINITY, l = 0.f, acc[8];
#pragma unroll
  for (int j = 0; j < 8; ++j) acc[j] = 0.f;

  for (int r = 0; r < R_; ++r) {
    int kvlen = lens[r * B_ + b];
    if (kvlen < 0) kvlen = 0;
    if (kvlen > M_) kvlen = M_;
    const int* btrow = bt + (r * B_ + b) * M_;
    const float* kb = kc + (size_t)r * P_ * HKD + (size_t)hk * D_ + ds;
    const float* vb = vc + (size_t)r * P_ * HKD + (size_t)hk * D_ + ds;

    for (int t = 0; t < kvlen; t += 4) {
      const int ta = t + tg;
      const bool va = ta < kvlen;
      const int pga = clampP(btrow[va ? ta : 0]);
      const size_t offa = (size_t)pga * HKD;
      float ka[8], wa[8];
      load8f(kb + offa, ka);
      load8f(vb + offa, wa);

      float da = 0.f;
#pragma unroll
      for (int j = 0; j < 8; ++j) da += qf[j] * ka[j];
#pragma unroll
      for (int msk = 1; msk <= 8; msk <<= 1) da += __shfl_xor(da, msk);

      const float sa = va ? da * SC2 : -INFINITY;
      const float mn = fmaxf(m, sa);
      if (mn == -INFINITY) continue;
      const float sc = (m > -INFINITY) ? exp2f(m - mn) : 0.f;
      const float pa = (sa > -INFINITY) ? exp2f(sa - mn) : 0.f;
      m = mn;
      l = l * sc + pa;
#pragma unroll
      for (int j = 0; j < 8; ++j) acc[j] = acc[j] * sc + pa * wa[j];
    }
  }

#pragma unroll
  for (int off = 16; off <= 32; off <<= 1) {
    const float mo = __shfl_xor(m, off);
    const float lo = __shfl_xor(l, off);
    float ao[8];
#pragma unroll
    for (int j = 0; j < 8; ++j) ao[j] = __shfl_xor(acc[j], off);
    const float mn = fmaxf(m, mo);
    const float se = (m > -INFINITY) ? exp2f(m - mn) : 0.f;
    const float so_ = (mo > -INFINITY) ? exp2f(mo - mn) : 0.f;
    l = l * se + lo * so_;
#pragma unroll
    for (int j = 0; j < 8; ++j) acc[j] = acc[j] * se + ao[j] * so_;
    m = mn;
  }

  if (lane < 16) {
    float inv = (l > 0.f) ? 1.0f / l : 0.f;
#pragma unroll
    for (int j = 0; j < 8; ++j)
      out[(size_t)(b * HQ_ + hk * G_ + g) * D_ + ds + j] = acc[j] * inv;
  }
}

extern "C" void kernel_launch(void* const* d_in, const int* in_sizes, int n_in,
                              void* d_out, int out_size, void* d_ws,
                              size_t ws_size, hipStream_t stream) {
  const float* q = (const float*)d_in[0];
  const float* kc = (const float*)d_in[1];
  const float* vc = (const float*)d_in[2];
  const int* lens = (const int*)d_in[3];
  const int* bt = (const int*)d_in[4];
  float* out = (float*)d_out;

  auto need = [](int s) {
    return (size_t)R_ * B_ * HK_ * s * (size_t)(2 * G_ + G_ * D_) *
           sizeof(float);
  };
  int S = 16;
  while (S > 1 && need(S) > ws_size) S >>= 1;

  if (need(S) <= ws_size) {
    const int nrec = R_ * B_ * HK_ * S;
    float* ws_m = (float*)d_ws;
    float* ws_l = ws_m + (size_t)nrec * G_;
    float* ws_o = ws_l + (size_t)nrec * G_;
    fd_partial<<<nrec, 256, 0, stream>>>(q, kc, vc, lens, bt, ws_m, ws_l,
                                         ws_o, S);
    fd_reduce<<<B_ * HK_ * G_, 128, 0, stream>>>(ws_m, ws_l, ws_o, out, S);
  } else {
    fd_mono<<<B_ * HK_, 256, 0, stream>>>(q, kc, vc, lens, bt, out);
  }
}

// Round 11
// 138.033 us; speedup vs baseline: 1.3431x; 1.3431x over previous
//
#include <hip/hip_runtime.h>
#include <math.h>

// flash-decode, GQA paged KV. R=4, B=16, Hq=32, Hk=8 (G=4), D=128, P=8192,
// PAGE=1, M=2048.
// Storage (confirmed round 7): q/k_cache/v_cache FLOAT32; lens/bt int32;
// out float32.
//
// Round 11 = round-8 structure (4 waves/block walk the SAME tokens in
// lockstep, wave = GQA head; L2 absorbs the 4x redundancy — round 10 proved
// splitting streams costs +20% FETCH) plus:
//  - slot-local online softmax (no per-iter cross-slot shfls)
//  - 2-deep software pipeline: named A/B K/V buffers, page indices loaded
//    2 iterations ahead so K/V loads issue with zero dependency
//  - log2-domain softmax (exp2f)

typedef float f32x4 __attribute__((ext_vector_type(4)));

#define R_ 4
#define B_ 16
#define HQ_ 32
#define HK_ 8
#define G_ 4
#define D_ 128
#define P_ 8192
#define M_ 2048
#define HKD (HK_ * D_)
#define SC2 (0.08838834764831845f * 1.4426950408889634f)  // scale * log2(e)

__device__ __forceinline__ void load8f(const float* p, float o[8]) {
  f32x4 a = *(const f32x4*)p;
  f32x4 b = *(const f32x4*)(p + 4);
#pragma unroll
  for (int j = 0; j < 4; ++j) { o[j] = a[j]; o[4 + j] = b[j]; }
}

__device__ __forceinline__ int clampP(int p) {
  return p < 0 ? 0 : (p >= P_ ? P_ - 1 : p);
}

// ---------------- kernel 1: per-(r,b,hk,split) partials ----------------
__global__ __launch_bounds__(256) void fd_partial(
    const float* __restrict__ q, const float* __restrict__ kc,
    const float* __restrict__ vc, const int* __restrict__ lens,
    const int* __restrict__ bt, float* __restrict__ ws_m,
    float* __restrict__ ws_l, float* __restrict__ ws_o, int S) {
  const int idx = blockIdx.x;
  const int s = idx % S;
  const int hk = (idx / S) % HK_;
  const int b = (idx / (S * HK_)) % B_;
  const int r = idx / (S * HK_ * B_);

  const int lane = threadIdx.x & 63;
  const int g = threadIdx.x >> 6;  // wave id == GQA sub-head
  const int tg = lane >> 4;        // slot 0..3 (2 tokens per slot per iter)
  const int ds = (lane & 15) * 8;  // dim slice [ds, ds+8)
  const int rec = blockIdx.x;      // == ((r*B+b)*HK + hk)*S + s

  int kvlen = lens[r * B_ + b];
  if (kvlen < 0) kvlen = 0;
  if (kvlen > M_) kvlen = M_;
  const int chunk = (kvlen + S - 1) / S;
  const int t0 = s * chunk;
  int t1 = t0 + chunk;
  if (t1 > kvlen) t1 = kvlen;
  if (t0 >= t1) {  // empty split: mark record invalid (block-uniform)
    if (lane == 0) ws_m[rec * G_ + g] = -INFINITY;
    return;
  }

  float qf[8];
  load8f(q + (size_t)(b * HQ_ + hk * G_ + g) * D_ + ds, qf);

  const int* btrow = bt + (r * B_ + b) * M_;
  const float* kb = kc + (size_t)r * P_ * HKD + (size_t)hk * D_ + ds;
  const float* vb = vc + (size_t)r * P_ * HKD + (size_t)hk * D_ + ds;

  // slot-local state
  float m = -INFINITY, l = 0.f, acc[8];
#pragma unroll
  for (int j = 0; j < 8; ++j) acc[j] = 0.f;

  const int tmax = t1 - 1;
  auto ti = [&](int t) { return t > tmax ? tmax : t; };  // t >= t0 >= 0

  auto compute = [&](int t, const float(&k0)[8], const float(&k1)[8],
                     const float(&v0)[8], const float(&v1)[8]) {
    const bool vld0 = (t + tg) < t1;
    const bool vld1 = (t + 4 + tg) < t1;
    float d0 = 0.f, d1 = 0.f;
#pragma unroll
    for (int j = 0; j < 8; ++j) {
      d0 += qf[j] * k0[j];
      d1 += qf[j] * k1[j];
    }
#pragma unroll
    for (int msk = 1; msk <= 8; msk <<= 1) {
      d0 += __shfl_xor(d0, msk);
      d1 += __shfl_xor(d1, msk);
    }
    const float s0 = vld0 ? d0 * SC2 : -INFINITY;
    const float s1 = vld1 ? d1 * SC2 : -INFINITY;
    const float mn = fmaxf(m, fmaxf(s0, s1));
    if (mn > -INFINITY) {  // slot-uniform branch
      const float sc = exp2f(m - mn);   // m=-inf -> 0
      const float p0 = exp2f(s0 - mn);  // -inf -> 0
      const float p1 = exp2f(s1 - mn);
      m = mn;
      l = l * sc + p0 + p1;
#pragma unroll
      for (int j = 0; j < 8; ++j)
        acc[j] = acc[j] * sc + p0 * v0[j] + p1 * v1[j];
    }
  };

  // pipeline: pages 2 halves ahead, K/V 1 half ahead (named A/B buffers)
  float k0A[8], k1A[8], v0A[8], v1A[8];
  float k0B[8], k1B[8], v0B[8], v1B[8];
  int pgA0 = clampP(btrow[ti(t0 + tg)]);
  int pgA1 = clampP(btrow[ti(t0 + 4 + tg)]);
  load8f(kb + (size_t)pgA0 * HKD, k0A);
  load8f(kb + (size_t)pgA1 * HKD, k1A);
  load8f(vb + (size_t)pgA0 * HKD, v0A);
  load8f(vb + (size_t)pgA1 * HKD, v1A);
  int pgB0 = clampP(btrow[ti(t0 + 8 + tg)]);
  int pgB1 = clampP(btrow[ti(t0 + 12 + tg)]);

  for (int t = t0; t < t1; t += 16) {
    {  // half 0: consume A, issue B loads (pages ready), refill A-pages
      load8f(kb + (size_t)pgB0 * HKD, k0B);
      load8f(kb + (size_t)pgB1 * HKD, k1B);
      load8f(vb + (size_t)pgB0 * HKD, v0B);
      load8f(vb + (size_t)pgB1 * HKD, v1B);
      pgA0 = clampP(btrow[ti(t + 16 + tg)]);
      pgA1 = clampP(btrow[ti(t + 20 + tg)]);
      compute(t, k0A, k1A, v0A, v1A);
    }
    if (t + 8 < t1) {  // half 1: consume B, issue A loads, refill B-pages
      load8f(kb + (size_t)pgA0 * HKD, k0A);
      load8f(kb + (size_t)pgA1 * HKD, k1A);
      load8f(vb + (size_t)pgA0 * HKD, v0A);
      load8f(vb + (size_t)pgA1 * HKD, v1A);
      pgB0 = clampP(btrow[ti(t + 24 + tg)]);
      pgB1 = clampP(btrow[ti(t + 28 + tg)]);
      compute(t + 8, k0B, k1B, v0B, v1B);
    }
  }

  // merge the 4 slot states (xor 16, 32); all lanes end with the total
#pragma unroll
  for (int off = 16; off <= 32; off <<= 1) {
    const float mo = __shfl_xor(m, off);
    const float lo = __shfl_xor(l, off);
    float ao[8];
#pragma unroll
    for (int j = 0; j < 8; ++j) ao[j] = __shfl_xor(acc[j], off);
    const float mn = fmaxf(m, mo);
    const float se = (m > -INFINITY) ? exp2f(m - mn) : 0.f;
    const float so_ = (mo > -INFINITY) ? exp2f(mo - mn) : 0.f;
    l = l * se + lo * so_;
#pragma unroll
    for (int j = 0; j < 8; ++j) acc[j] = acc[j] * se + ao[j] * so_;
    m = mn;
  }

  if (lane < 16) {
#pragma unroll
    for (int j = 0; j < 8; ++j)
      ws_o[((size_t)rec * G_ + g) * D_ + ds + j] = acc[j];
    if (lane == 0) {
      ws_m[rec * G_ + g] = m;  // log2-domain
      ws_l[rec * G_ + g] = l;
    }
  }
}

// ---------------- kernel 2: LSE-weighted combine over R*S ----------------
__global__ __launch_bounds__(128) void fd_reduce(
    const float* __restrict__ ws_m, const float* __restrict__ ws_l,
    const float* __restrict__ ws_o, float* __restrict__ out, int S) {
  const int row = blockIdx.x;  // (b*HK + hk)*G + g
  const int g = row % G_;
  const int hk = (row / G_) % HK_;
  const int b = row / (G_ * HK_);
  const int d = threadIdx.x;

  float mf = -INFINITY;
  for (int r = 0; r < R_; ++r)
    for (int s = 0; s < S; ++s) {
      int rec = ((r * B_ + b) * HK_ + hk) * S + s;
      mf = fmaxf(mf, ws_m[rec * G_ + g]);
    }
  float of = 0.f, lf = 0.f;
  for (int r = 0; r < R_; ++r)
    for (int s = 0; s < S; ++s) {
      int rec = ((r * B_ + b) * HK_ + hk) * S + s;
      float wm = ws_m[rec * G_ + g];
      if (wm == -INFINITY) continue;
      float wt = exp2f(wm - mf);  // log2-domain partials
      of += wt * ws_o[((size_t)rec * G_ + g) * D_ + d];
      lf += wt * ws_l[rec * G_ + g];
    }
  out[(size_t)(b * HQ_ + hk * G_ + g) * D_ + d] = of / lf;
}

// ---------------- fallback: monolithic (tiny workspace) ----------------
__global__ __launch_bounds__(256) void fd_mono(
    const float* __restrict__ q, const float* __restrict__ kc,
    const float* __restrict__ vc, const int* __restrict__ lens,
    const int* __restrict__ bt, float* __restrict__ out) {
  const int hk = blockIdx.x % HK_;
  const int b = blockIdx.x / HK_;
  const int lane = threadIdx.x & 63;
  const int g = threadIdx.x >> 6;
  const int tg = lane >> 4;
  const int ds = (lane & 15) * 8;

  float qf[8];
  load8f(q + (size_t)(b * HQ_ + hk * G_ + g) * D_ + ds, qf);

  float m = -INFINITY, l = 0.f, acc[8];
#pragma unroll
  for (int j = 0; j < 8; ++j) acc[j] = 0.f;

  for (int r = 0; r < R_; ++r) {
    int kvlen = lens[r * B_ + b];
    if (kvlen < 0) kvlen = 0;
    if (kvlen > M_) kvlen = M_;
    const int* btrow = bt + (r * B_ + b) * M_;
    const float* kb = kc + (size_t)r * P_ * HKD + (size_t)hk * D_ + ds;
    const float* vb = vc + (size_t)r * P_ * HKD + (size_t)hk * D_ + ds;

    for (int t = 0; t < kvlen; t += 4) {
      const int ta = t + tg;
      const bool va = ta < kvlen;
      const int pga = clampP(btrow[va ? ta : 0]);
      const size_t offa = (size_t)pga * HKD;
      float ka[8], wa[8];
      load8f(kb + offa, ka);
      load8f(vb + offa, wa);

      float da = 0.f;
#pragma unroll
      for (int j = 0; j < 8; ++j) da += qf[j] * ka[j];
#pragma unroll
      for (int msk = 1; msk <= 8; msk <<= 1) da += __shfl_xor(da, msk);

      const float sa = va ? da * SC2 : -INFINITY;
      const float mn = fmaxf(m, sa);
      if (mn > -INFINITY) {
        const float sc = exp2f(m - mn);
        const float pa = exp2f(sa - mn);
        m = mn;
        l = l * sc + pa;
#pragma unroll
        for (int j = 0; j < 8; ++j) acc[j] = acc[j] * sc + pa * wa[j];
      }
    }
  }

#pragma unroll
  for (int off = 16; off <= 32; off <<= 1) {
    const float mo = __shfl_xor(m, off);
    const float lo = __shfl_xor(l, off);
    float ao[8];
#pragma unroll
    for (int j = 0; j < 8; ++j) ao[j] = __shfl_xor(acc[j], off);
    const float mn = fmaxf(m, mo);
    const float se = (m > -INFINITY) ? exp2f(m - mn) : 0.f;
    const float so_ = (mo > -INFINITY) ? exp2f(mo - mn) : 0.f;
    l = l * se + lo * so_;
#pragma unroll
    for (int j = 0; j < 8; ++j) acc[j] = acc[j] * se + ao[j] * so_;
    m = mn;
  }

  if (lane < 16) {
    float inv = (l > 0.f) ? 1.0f / l : 0.f;
#pragma unroll
    for (int j = 0; j < 8; ++j)
      out[(size_t)(b * HQ_ + hk * G_ + g) * D_ + ds + j] = acc[j] * inv;
  }
}

extern "C" void kernel_launch(void* const* d_in, const int* in_sizes, int n_in,
                              void* d_out, int out_size, void* d_ws,
                              size_t ws_size, hipStream_t stream) {
  const float* q = (const float*)d_in[0];
  const float* kc = (const float*)d_in[1];
  const float* vc = (const float*)d_in[2];
  const int* lens = (const int*)d_in[3];
  const int* bt = (const int*)d_in[4];
  float* out = (float*)d_out;

  auto need = [](int s) {
    return (size_t)R_ * B_ * HK_ * s * (size_t)(2 * G_ + G_ * D_) *
           sizeof(float);
  };
  int S = 16;
  while (S > 1 && need(S) > ws_size) S >>= 1;

  if (need(S) <= ws_size) {
    const int nrec = R_ * B_ * HK_ * S;
    float* ws_m = (float*)d_ws;
    float* ws_l = ws_m + (size_t)nrec * G_;
    float* ws_o = ws_l + (size_t)nrec * G_;
    fd_partial<<<nrec, 256, 0, stream>>>(q, kc, vc, lens, bt, ws_m, ws_l,
                                         ws_o, S);
    fd_reduce<<<B_ * HK_ * G_, 128, 0, stream>>>(ws_m, ws_l, ws_o, out, S);
  } else {
    fd_mono<<<B_ * HK_, 256, 0, stream>>>(q, kc, vc, lens, bt, out);
  }
}